// Round 6
// baseline (95.359 us; speedup 1.0000x reference)
//
#include <hip/hip_runtime.h>

#define Bn 8
#define Nn 2048
#define Dn 128
#define OUTn 128

typedef __attribute__((ext_vector_type(8))) short bf16x8;     // MFMA A/B operand (8 bf16)
typedef __attribute__((ext_vector_type(8))) unsigned short ushort8;
typedef __attribute__((ext_vector_type(4))) float f32x4;      // MFMA C/D
typedef __attribute__((ext_vector_type(4))) int int4v;
typedef __attribute__((ext_vector_type(4))) float float4v;

__device__ __forceinline__ unsigned short f2bf(float f) {
  unsigned int u = __builtin_bit_cast(unsigned int, f);
  u += 0x7FFFu + ((u >> 16) & 1u);   // round-to-nearest-even
  return (unsigned short)(u >> 16);
}

// ---------------- prep: transpose input + transpose W ----------------
// blocks 0..255: input [b][n][d] fp32 -> inT [b][d][n] bf16
// blocks 256..383: W [2D][OUT] fp32 -> WT [OUT][2D] bf16
__global__ __launch_bounds__(256) void gcn_prep(const float* __restrict__ in,
                                                const float* __restrict__ W,
                                                unsigned short* __restrict__ inT,
                                                unsigned short* __restrict__ WT) {
  const int tid = threadIdx.x;
  if (blockIdx.x >= 256) {
    int gid = (blockIdx.x - 256) * 256 + tid;    // 0..32767
    int j = gid >> 8, k = gid & 255;             // WT[j][k] = W[k][j]
    WT[gid] = f2bf(W[k * OUTn + j]);
    return;
  }
  const int b = blockIdx.x >> 5;
  const int n0 = (blockIdx.x & 31) * 64;
  __shared__ __attribute__((aligned(16))) unsigned short lds[64][130];
  #pragma unroll
  for (int c = 0; c < 32; ++c) {
    int e = tid + c * 256;
    int i = e >> 7, d = e & 127;
    lds[i][d] = f2bf(in[((size_t)(b * Nn + n0 + i)) * Dn + d]);
  }
  __syncthreads();
  #pragma unroll
  for (int c = 0; c < 4; ++c) {
    int ch = tid + c * 256;
    int d = ch >> 3, g = (ch & 7) * 8;
    ushort8 v;
    #pragma unroll
    for (int e = 0; e < 8; ++e) v[e] = lds[g + e][d];
    *(ushort8*)(inT + ((size_t)(b * Dn + d)) * Nn + n0 + g) = v;
  }
}

// ---------------- main: barrier-free K-loop, waves split K ----------------
// 1024 blocks x 256 threads (4 waves). Block = 16 rows of one batch.
// Wave wv owns K-chunk [wv*512, wv*512+512): 16 steps x 8 MFMA (16 rows x 128 cols).
// A-frags DIRECT from adj (lanes {lr,lr+16,lr+32,lr+48} = one 128B line of row lr),
// 2-deep reg prefetch. B-frags DIRECT from L2-hot inT. NO LDS / barriers in loop.
// Epilogue: cross-kc reduce + degree + GEMM2 + sigmoid + L2-norm in 35KB LDS union.
union EpiSMem {
  float buf[4][16][136];                     // 34816 B: per-kc partial C
  struct {
    unsigned short aggl[16][136];            // bf16 agg for GEMM2 A-frags
    float rowsum[16][4];
  } e;
};

__global__ __launch_bounds__(256, 4) void gcn_main(
    const float* __restrict__ input_, const int* __restrict__ adj,
    const float* __restrict__ bvec, const unsigned short* __restrict__ inT,
    const unsigned short* __restrict__ WT, float* __restrict__ out) {
  __shared__ EpiSMem sm;
  __shared__ float degp[4][16];

  const int tid = threadIdx.x;
  const int wv = tid >> 6;                   // = K-chunk index 0..3
  const int l = tid & 63, lr = l & 15, lg = l >> 4;

  // bijective XCD swizzle: 1024 blocks (%8==0) -> XCD x gets one batch
  const int swz = (blockIdx.x & 7) * 128 + (blockIdx.x >> 3);
  const int bb = swz >> 7;
  const int row0 = (swz & 127) * 16;
  const int grow0 = bb * Nn + row0;

  // per-lane stream bases
  const int* arow = adj + (size_t)(grow0 + lr) * Nn + wv * 512 + lg * 8;
  const unsigned short* binT = inT + (size_t)bb * Dn * Nn + (size_t)lr * Nn +
                               wv * 512 + lg * 8;

  f32x4 acc[8] = {};
  int dsum = 0;

  // A pipeline: 2-deep register prefetch (cur = step it, nxt = step it+1)
  int4v aCur0 = *(const int4v*)(arow);
  int4v aCur1 = *(const int4v*)(arow + 4);
  int4v aNxt0 = *(const int4v*)(arow + 32);
  int4v aNxt1 = *(const int4v*)(arow + 36);

  #pragma unroll
  for (int it = 0; it < 16; ++it) {
    // convert current 8 ints -> bf16 frag; count degree
    ushort8 av;
    #pragma unroll
    for (int e = 0; e < 4; ++e) {
      int v0 = aCur0[e], v1 = aCur1[e];
      dsum += (v0 != 0) + (v1 != 0);
      av[e]     = (v0 != 0) ? (unsigned short)0x3F80u : (unsigned short)0u;
      av[e + 4] = (v1 != 0) ? (unsigned short)0x3F80u : (unsigned short)0u;
    }
    bf16x8 af = __builtin_bit_cast(bf16x8, av);
    // rotate pipeline, issue step it+2 (stays in flight through the MFMAs)
    aCur0 = aNxt0; aCur1 = aNxt1;
    if (it + 2 < 16) {
      aNxt0 = *(const int4v*)(arow + (it + 2) * 32);
      aNxt1 = *(const int4v*)(arow + (it + 2) * 32 + 4);
    }
    // 8 col-frags direct from L2-hot inT
    #pragma unroll
    for (int cf = 0; cf < 8; ++cf) {
      bf16x8 bfm = *(const bf16x8*)(binT + (size_t)cf * 16 * Nn + it * 32);
      acc[cf] = __builtin_amdgcn_mfma_f32_16x16x32_bf16(af, bfm, acc[cf], 0, 0, 0);
    }
  }

  // ---- per-kc partials to LDS; degree partial per row ----
  #pragma unroll
  for (int cf = 0; cf < 8; ++cf)
    #pragma unroll
    for (int reg = 0; reg < 4; ++reg)
      sm.buf[wv][lg * 4 + reg][cf * 16 + lr] = acc[cf][reg];
  {
    int s = dsum;
    s += __shfl_xor(s, 16);
    s += __shfl_xor(s, 32);                  // lanes {lr,+16,+32,+48} summed
    if (l < 16) degp[wv][lr] = (float)s;
  }
  __syncthreads();

  // ---- sum 4 kc-partials, /deg, pack bf16 (held in regs; buf is re-used) ----
  const int row = tid >> 4, c0 = (tid & 15) * 8;
  float dg = degp[0][row] + degp[1][row] + degp[2][row] + degp[3][row];
  if (dg == 0.f) dg = 1.f;
  const float inv = 1.f / dg;
  ushort8 packed;
  #pragma unroll
  for (int e = 0; e < 8; ++e) {
    float ssum = sm.buf[0][row][c0 + e] + sm.buf[1][row][c0 + e] +
                 sm.buf[2][row][c0 + e] + sm.buf[3][row][c0 + e];
    packed[e] = f2bf(ssum * inv);
  }
  __syncthreads();                           // buf reads done before aliased write
  *(ushort8*)&sm.e.aggl[row][c0] = packed;
  __syncthreads();

  // ---- GEMM2: [x | agg] @ W (K=256); x direct from input_, B from WT ----
  f32x4 acc2[2] = {};
  const float* xrow = input_ + (size_t)(grow0 + lr) * Dn;
  #pragma unroll
  for (int ks = 0; ks < 8; ++ks) {
    bf16x8 af;
    if (ks < 4) {
      float4v f0 = *(const float4v*)(xrow + ks * 32 + lg * 8);
      float4v f1 = *(const float4v*)(xrow + ks * 32 + lg * 8 + 4);
      ushort8 vv;
      #pragma unroll
      for (int e = 0; e < 4; ++e) { vv[e] = f2bf(f0[e]); vv[e + 4] = f2bf(f1[e]); }
      af = __builtin_bit_cast(bf16x8, vv);
    } else {
      af = *(const bf16x8*)&sm.e.aggl[lr][(ks - 4) * 32 + lg * 8];
    }
    #pragma unroll
    for (int cf = 0; cf < 2; ++cf) {
      bf16x8 bw = *(const bf16x8*)(WT + (size_t)(wv * 32 + cf * 16 + lr) * 256 +
                                   ks * 32 + lg * 8);
      acc2[cf] = __builtin_amdgcn_mfma_f32_16x16x32_bf16(af, bw, acc2[cf], 0, 0, 0);
    }
  }

  // ---- bias + sigmoid + row L2-norm + store ----
  float bcol[2];
  bcol[0] = bvec[wv * 32 + lr];
  bcol[1] = bvec[wv * 32 + 16 + lr];
  float sg[2][4];
  #pragma unroll
  for (int cf = 0; cf < 2; ++cf)
    #pragma unroll
    for (int reg = 0; reg < 4; ++reg) {
      float x = acc2[cf][reg] + bcol[cf];
      sg[cf][reg] = 1.0f / (1.0f + expf(-x));
    }
  #pragma unroll
  for (int reg = 0; reg < 4; ++reg) {
    float p = sg[0][reg] * sg[0][reg] + sg[1][reg] * sg[1][reg];
    p += __shfl_xor(p, 1);
    p += __shfl_xor(p, 2);
    p += __shfl_xor(p, 4);
    p += __shfl_xor(p, 8);
    if (lr == 0) sm.e.rowsum[lg * 4 + reg][wv] = p;
  }
  __syncthreads();
  #pragma unroll
  for (int reg = 0; reg < 4; ++reg) {
    const int r2 = lg * 4 + reg;
    float nrm = rsqrtf(sm.e.rowsum[r2][0] + sm.e.rowsum[r2][1] +
                       sm.e.rowsum[r2][2] + sm.e.rowsum[r2][3]);
    #pragma unroll
    for (int cf = 0; cf < 2; ++cf)
      out[(size_t)(grow0 + r2) * OUTn + wv * 32 + cf * 16 + lr] =
          sg[cf][reg] * nrm;
  }
}

extern "C" void kernel_launch(void* const* d_in, const int* in_sizes, int n_in,
                              void* d_out, int out_size, void* d_ws, size_t ws_size,
                              hipStream_t stream) {
  (void)in_sizes; (void)n_in; (void)out_size; (void)ws_size;
  const float* input_ = (const float*)d_in[0];
  const int* adj = (const int*)d_in[1];
  const float* W = (const float*)d_in[2];
  const float* bvec = (const float*)d_in[3];
  float* out = (float*)d_out;

  unsigned short* inT = (unsigned short*)d_ws;                 // 4 MB
  unsigned short* WT = inT + (size_t)Bn * Dn * Nn;             // 64 KB

  hipLaunchKernelGGL(gcn_prep, dim3(384), dim3(256), 0, stream, input_, W, inT, WT);
  hipLaunchKernelGGL(gcn_main, dim3(1024), dim3(256), 0, stream,
                     input_, adj, bvec, inT, WT, out);
}